// Round 8
// baseline (141.266 us; speedup 1.0000x reference)
//
#include <hip/hip_runtime.h>
#include <hip/hip_bf16.h>
#include <stdint.h>

typedef unsigned short u16;
typedef __attribute__((ext_vector_type(8))) short bf16x8;
typedef __attribute__((ext_vector_type(8))) _Float16 f16x8;
typedef __attribute__((ext_vector_type(4))) float f32x4;
typedef __attribute__((ext_vector_type(16))) float f32x16;
typedef __attribute__((ext_vector_type(4))) u16 u16x4;
typedef __attribute__((ext_vector_type(4))) float f4v;

#define DEV __device__ __forceinline__

DEV u16 f2bf(float x) {
    union { float f; uint32_t u; } v; v.f = x;
    uint32_t r = v.u + 0x7FFF + ((v.u >> 16) & 1);
    return (u16)(r >> 16);
}

DEV float fexp2(float x) {
    float r;
    asm("v_exp_f32 %0, %1" : "=v"(r) : "v"(x));
    return r;
}

DEV f32x4 mfma16(bf16x8 a, bf16x8 b, f32x4 c) {
    return __builtin_amdgcn_mfma_f32_16x16x32_bf16(a, b, c, 0, 0, 0);
}
DEV f32x4 mfma16h(f16x8 a, f16x8 b, f32x4 c) {
    return __builtin_amdgcn_mfma_f32_16x16x32_f16(a, b, c, 0, 0, 0);
}
DEV f32x16 mfma32(bf16x8 a, bf16x8 b, f32x16 c) {
    return __builtin_amdgcn_mfma_f32_32x32x16_bf16(a, b, c, 0, 0, 0);
}

DEV void gld_lds16(const u16* g, u16* lds) {
    __builtin_amdgcn_global_load_lds(
        (const __attribute__((address_space(1))) void*)g,
        (__attribute__((address_space(3))) void*)lds, 16, 0, 0);
}

#define VMCNT2 asm volatile("s_waitcnt vmcnt(2)" ::: "memory")
#define VMCNT0 asm volatile("s_waitcnt vmcnt(0)" ::: "memory")
#define BAR() __builtin_amdgcn_s_barrier()

DEV u16 h2u(_Float16 h) { union { _Float16 h; u16 u; } v; v.h = h; return v.u; }

// ---------------- Pass A: fused X-split (fp16 hi/lo) + W-cast ----------------
struct PrepArgs {
    const float* src[6];
    u16* hi[6];
    u16* lo[6];   // null -> cast-only
    int n4[6];
};

__global__ __launch_bounds__(256) void prep_kernel(PrepArgs a) {
    const int z = blockIdx.y;
    const f4v* __restrict__ src = (const f4v*)a.src[z];
    u16x4* __restrict__ hi = (u16x4*)a.hi[z];
    u16x4* __restrict__ lo = (u16x4*)a.lo[z];
    const int n4 = a.n4[z];
    int i = blockIdx.x * blockDim.x + threadIdx.x;
    const int stride = gridDim.x * blockDim.x;
    if (lo) {
        for (; i < n4; i += stride) {
            f4v x = src[i];
            u16x4 h, l;
#pragma unroll
            for (int c = 0; c < 4; ++c) {
                float xv = x[c];
                _Float16 hb = (_Float16)xv;
                float r = xv - (float)hb;
                h[c] = h2u(hb);
                l[c] = h2u((_Float16)r);
            }
            hi[i] = h;
            lo[i] = l;
        }
    } else {
        for (; i < n4; i += stride) {
            f4v x = src[i];
            u16x4 d;
#pragma unroll
            for (int c = 0; c < 4; ++c) d[c] = h2u((_Float16)x[c]);
            hi[i] = d;
        }
    }
}

// ---------------- Pass B: projections — 256x256 tile, 8-wave, 8-phase (round-6) ----------------
struct ProjArgs {
    const u16* xhi[3];
    const u16* xlo[3];
    const u16* wf[3];
    u16* outq;
    u16* outk;
    u16* outvt;
};

__global__ __launch_bounds__(512, 2) void proj_kernel(ProjArgs args) {
    __shared__ u16 lds[2][32768];

    const int tid = threadIdx.x;
    const int w = tid >> 6, l = tid & 63;
    const int fr = l & 15, fg = l >> 4;
    const int wa = w >> 2, wb = w & 3;

    const int b0 = blockIdx.x;
    const int swz = (b0 & 7) * 24 + (b0 >> 3);
    const int z = swz >> 6;
    const int r = swz & 63;

    int ta, tb;
    const u16 *A0, *A1, *B0, *B1;
    if (z < 2) {
        ta = r & 3; tb = r >> 2;
        A0 = args.wf[z]; A1 = args.wf[z];
        B0 = args.xhi[z]; B1 = args.xlo[z];
    } else {
        ta = r >> 2; tb = r & 3;
        A0 = args.xhi[2]; A1 = args.xlo[2];
        B0 = args.wf[2]; B1 = args.wf[2];
    }

    const int s_r = tid >> 3;
    const int s_c = (((tid & 7) ^ (s_r & 7)) << 3);
    const size_t aoff = (size_t)(ta * 256 + s_r) * 1024 + s_c;
    const size_t boff = (size_t)(tb * 256 + s_r) * 1024 + s_c;

    const int abase = (wa * 128 + fr) * 64;
    const int bbase = 16384 + (wb * 64 + fr) * 64;
    const int sl0 = ((fg) ^ (fr & 7)) << 3;
    const int sl1 = ((4 + fg) ^ (fr & 7)) << 3;

    f32x4 acc[8][4];
#pragma unroll
    for (int mi = 0; mi < 8; ++mi)
#pragma unroll
        for (int ni = 0; ni < 4; ++ni)
            acc[mi][ni] = (f32x4){0.f, 0.f, 0.f, 0.f};

#define STAGE2(SRC, OFFBASE, REGION, HALF, BUFN, KTN)                               \
    do {                                                                            \
        _Pragma("unroll")                                                           \
        for (int j = 0; j < 2; ++j) {                                               \
            gld_lds16((SRC) + (OFFBASE) + (size_t)((HALF) * 128 + j * 64) * 1024    \
                           + (size_t)(KTN) * 64,                                    \
                      &lds[BUFN][(REGION) + (HALF) * 8192 + j * 4096 + w * 512]);   \
        }                                                                           \
    } while (0)

#pragma unroll
    for (int h = 0; h < 2; ++h) {
#pragma unroll
        for (int j = 0; j < 2; ++j) {
            gld_lds16(A0 + aoff + (size_t)(h * 128 + j * 64) * 1024,
                      &lds[0][h * 8192 + j * 4096 + w * 512]);
            gld_lds16(B0 + boff + (size_t)(h * 128 + j * 64) * 1024,
                      &lds[0][16384 + h * 8192 + j * 4096 + w * 512]);
        }
    }

#define PHASE(MQ0, STAGECALL)                                                       \
    do {                                                                            \
        if (more) STAGECALL;                                                        \
        f16x8 p00 = *(const f16x8*)&Lb[abase + (MQ0) * 1024 + sl0];                 \
        f16x8 p01 = *(const f16x8*)&Lb[abase + (MQ0) * 1024 + sl1];                 \
        f16x8 p10 = *(const f16x8*)&Lb[abase + (MQ0 + 1) * 1024 + sl0];             \
        f16x8 p11 = *(const f16x8*)&Lb[abase + (MQ0 + 1) * 1024 + sl1];             \
        BAR();                                                                      \
        __builtin_amdgcn_s_setprio(1);                                              \
        _Pragma("unroll")                                                           \
        for (int ni = 0; ni < 4; ++ni) {                                            \
            acc[MQ0][ni] = mfma16h(p00, Bf0[ni], acc[MQ0][ni]);                     \
            acc[MQ0][ni] = mfma16h(p01, Bf1[ni], acc[MQ0][ni]);                     \
            acc[MQ0 + 1][ni] = mfma16h(p10, Bf0[ni], acc[MQ0 + 1][ni]);             \
            acc[MQ0 + 1][ni] = mfma16h(p11, Bf1[ni], acc[MQ0 + 1][ni]);             \
        }                                                                           \
        __builtin_amdgcn_s_setprio(0);                                              \
        BAR();                                                                      \
    } while (0)

#pragma unroll 1
    for (int t = 0; t < 32; ++t) {
        const int buf = t & 1;
        const int nbuf = buf ^ 1;
        const int tn = t + 1;
        const bool more = (tn < 32);
        const int termn = tn >> 4;
        const int ktn = tn & 15;
        const u16* An = termn ? A1 : A0;
        const u16* Bn = termn ? B1 : B0;
        const u16* Lb = &lds[buf][0];

        f16x8 Bf0[4], Bf1[4];

        if (more) STAGE2(An, aoff, 0, 0, nbuf, ktn);
        if (more) { VMCNT2; } else { VMCNT0; }
        BAR();
        {
            f16x8 a00 = *(const f16x8*)&Lb[abase + sl0];
            f16x8 a01 = *(const f16x8*)&Lb[abase + sl1];
            f16x8 a10 = *(const f16x8*)&Lb[abase + 1024 + sl0];
            f16x8 a11 = *(const f16x8*)&Lb[abase + 1024 + sl1];
#pragma unroll
            for (int ni = 0; ni < 4; ++ni) {
                Bf0[ni] = *(const f16x8*)&Lb[bbase + ni * 1024 + sl0];
                Bf1[ni] = *(const f16x8*)&Lb[bbase + ni * 1024 + sl1];
            }
            BAR();
            __builtin_amdgcn_s_setprio(1);
#pragma unroll
            for (int ni = 0; ni < 4; ++ni) {
                acc[0][ni] = mfma16h(a00, Bf0[ni], acc[0][ni]);
                acc[0][ni] = mfma16h(a01, Bf1[ni], acc[0][ni]);
                acc[1][ni] = mfma16h(a10, Bf0[ni], acc[1][ni]);
                acc[1][ni] = mfma16h(a11, Bf1[ni], acc[1][ni]);
            }
            __builtin_amdgcn_s_setprio(0);
            BAR();
        }
        PHASE(2, STAGE2(An, aoff, 0, 1, nbuf, ktn));
        PHASE(4, STAGE2(Bn, boff, 16384, 0, nbuf, ktn));
        PHASE(6, STAGE2(Bn, boff, 16384, 1, nbuf, ktn));
    }
#undef PHASE
#undef STAGE2

    if (z < 2) {
        u16* outp = (z == 0) ? args.outq : args.outk;
#pragma unroll
        for (int mq = 0; mq < 8; ++mq) {
#pragma unroll
            for (int ni = 0; ni < 4; ++ni) {
                const int e0 = ta * 256 + wa * 128 + mq * 16 + fg * 4;
                const int m = tb * 256 + wb * 64 + ni * 16 + fr;
                const int n = (m >> 11) * 16 + (e0 >> 6);
                const int s = m & 2047;
                u16x4 pk;
#pragma unroll
                for (int rr = 0; rr < 4; ++rr) pk[rr] = f2bf(acc[mq][ni][rr]);
                *(u16x4*)&outp[((size_t)(n * 2048 + s)) * 64 + (e0 & 63)] = pk;
            }
        }
    } else {
        u16* outp = args.outvt;
#pragma unroll
        for (int mq = 0; mq < 8; ++mq) {
#pragma unroll
            for (int ni = 0; ni < 4; ++ni) {
                const int m0 = ta * 256 + wa * 128 + mq * 16 + fg * 4;
                const int e = tb * 256 + wb * 64 + ni * 16 + fr;
                const int n = (m0 >> 11) * 16 + (e >> 6);
                u16x4 pk;
#pragma unroll
                for (int rr = 0; rr < 4; ++rr) pk[rr] = f2bf(acc[mq][ni][rr]);
                *(u16x4*)&outp[((size_t)(n * 64 + (e & 63))) * 2048 + (m0 & 2047)] = pk;
            }
        }
    }
}

// ---------------- Pass C: flash attention, 32x32 MFMA, 32 q-rows/wave ----------------
// Swapped QK^T: D=S^T, lane holds col q=lane&31. K stored in LDS with key bits 2<->3
// swapped, so each lane's 16 D-regs ARE the PV B-operand keys {W*16 + hi*8 + j} in
// register order — softmax AND P-redistribution fully lane-local (no cross-lane).
// 4 waves/block, 128 q/block, KVBLK=64, double-buffered reg-staged LDS.
__global__ __launch_bounds__(256) void attn_kernel(const u16* __restrict__ qh,
                                                   const u16* __restrict__ kh,
                                                   const u16* __restrict__ vt,
                                                   float* __restrict__ out) {
    __shared__ u16 lds[2][8192];   // [buf][ K: 64x64 | V(+4096): 64x64 ]

    const int tid = threadIdx.x;
    const int w = tid >> 6, l = tid & 63;
    const int hi = l >> 5, lq = l & 31;
    const int rot = lq & 7;

    const int b = blockIdx.x;
    const int n = (b & 7) * 4 + ((b >> 3) >> 4);   // head-batch 0..31
    const int qt = (b >> 3) & 15;
    const int qrow0 = qt * 128 + w * 32 + lq;      // lane's q row (global s)
    const float cs = 0.125f * 1.44269504088896f;   // (1/sqrt(dk)) * log2(e)

    const u16* khn = kh + (size_t)n * 2048 * 64;
    const u16* vtn = vt + (size_t)n * 64 * 2048;

    // Q B-frags: col q = lq, k = f*16 + hi*8 + j
    const u16* qrow = qh + ((size_t)n * 2048 + qrow0) * 64;
    bf16x8 qf[4];
#pragma unroll
    for (int f = 0; f < 4; ++f)
        qf[f] = *(const bf16x8*)(qrow + f * 16 + hi * 8);

    // ---- staging geometry (256 threads; 2 K-rows + 2 V-rows each) ----
    const int srow = tid >> 3;          // 0..31
    const int sch = tid & 7;
    // K physical row: swap bits 2<->3 of key row (involution)
    const int pr0 = (srow & 19) | ((srow & 4) << 1) | ((srow & 8) >> 1);
    const int kslot = ((sch + (pr0 & 7)) & 7) * 8;
    const int kw0 = pr0 * 64 + kslot;
    const int kw1 = (pr0 + 32) * 64 + kslot;
    const int vslot = ((sch + (srow & 7)) & 7) * 8;
    const int vw0 = 4096 + srow * 64 + vslot;
    const int vw1 = 4096 + (srow + 32) * 64 + vslot;

    f32x16 acc0, acc1;
#pragma unroll
    for (int rr = 0; rr < 16; ++rr) { acc0[rr] = 0.f; acc1[rr] = 0.f; }
    float mrun = -INFINITY;
    float lsum = 0.f;

    bf16x8 kr0, kr1, vr0, vr1;

#define STAGE_LOAD(kb_) do {                                                        \
        kr0 = *(const bf16x8*)(khn + (size_t)((kb_) * 64 + srow) * 64 + sch * 8);   \
        kr1 = *(const bf16x8*)(khn + (size_t)((kb_) * 64 + srow + 32) * 64 + sch * 8);\
        vr0 = *(const bf16x8*)(vtn + (size_t)srow * 2048 + (kb_) * 64 + sch * 8);   \
        vr1 = *(const bf16x8*)(vtn + (size_t)(srow + 32) * 2048 + (kb_) * 64 + sch * 8);\
    } while (0)

#define STAGE_WRITE(buf_) do {                                                      \
        *(bf16x8*)&lds[buf_][kw0] = kr0;                                            \
        *(bf16x8*)&lds[buf_][kw1] = kr1;                                            \
        *(bf16x8*)&lds[buf_][vw0] = vr0;                                            \
        *(bf16x8*)&lds[buf_][vw1] = vr1;                                            \
    } while (0)

    STAGE_LOAD(0);
    STAGE_WRITE(0);
    STAGE_LOAD(1);
    __syncthreads();

    for (int kb = 0; kb < 32; ++kb) {
        const int cur = kb & 1;
        const u16* Kb = &lds[cur][0];

        // ---- QK^T: sf0 = keys[0..31], sf1 = keys[32..63] (bit-2/3-permuted) ----
        f32x16 sf0, sf1;
#pragma unroll
        for (int rr = 0; rr < 16; ++rr) { sf0[rr] = 0.f; sf1[rr] = 0.f; }
#pragma unroll
        for (int f = 0; f < 4; ++f) {
            bf16x8 a0 = *(const bf16x8*)&Kb[lq * 64 + ((2 * f + hi + rot) & 7) * 8];
            sf0 = mfma32(a0, qf[f], sf0);
        }
#pragma unroll
        for (int f = 0; f < 4; ++f) {
            bf16x8 a1 = *(const bf16x8*)&Kb[2048 + lq * 64 + ((2 * f + hi + rot) & 7) * 8];
            sf1 = mfma32(a1, qf[f], sf1);
        }

        // ---- row max (lane-local 32 + pair lane) ----
        float t8[8];
#pragma unroll
        for (int i = 0; i < 8; ++i)
            t8[i] = fmaxf(fmaxf(sf0[2 * i], sf0[2 * i + 1]),
                          fmaxf(sf1[2 * i], sf1[2 * i + 1]));
        float cm = fmaxf(fmaxf(fmaxf(t8[0], t8[1]), fmaxf(t8[2], t8[3])),
                         fmaxf(fmaxf(t8[4], t8[5]), fmaxf(t8[6], t8[7])));
        cm = fmaxf(cm, __shfl_xor(cm, 32, 64));

        if (__any(cm > mrun)) {
            float mnew = fmaxf(mrun, cm);
            float sc = fexp2(cs * (mrun - mnew));
            mrun = mnew;
            lsum *= sc;
#pragma unroll
            for (int rr = 0; rr < 16; ++rr) { acc0[rr] *= sc; acc1[rr] *= sc; }
        }

        // ---- p = exp2(cs*s - cs*m), accumulate row-sum ----
        const float negm = -cs * mrun;
#pragma unroll
        for (int rr = 0; rr < 16; ++rr) {
            sf0[rr] = fexp2(fmaf(cs, sf0[rr], negm));
            sf1[rr] = fexp2(fmaf(cs, sf1[rr], negm));
            lsum += sf0[rr] + sf1[rr];
        }

        // ---- PV: per 16-key window, B-frag = own regs [W*8..W*8+7] packed ----
#pragma unroll
        for (int ks = 0; ks < 2; ++ks) {
#pragma unroll
            for (int W = 0; W < 2; ++W) {
                union { bf16x8 v; uint32_t u[4]; } bf_;
#pragma unroll
                for (int j2 = 0; j2 < 4; ++j2) {
                    float lo = ks ? sf1[W * 8 + 2 * j2] : sf0[W * 8 + 2 * j2];
                    float hv = ks ? sf1[W * 8 + 2 * j2 + 1] : sf0[W * 8 + 2 * j2 + 1];
                    asm("v_cvt_pk_bf16_f32 %0, %1, %2" : "=v"(bf_.u[j2]) : "v"(lo), "v"(hv));
                }
                const int s2 = ks * 2 + W;
                const int vsl = ((2 * s2 + hi + rot) & 7) * 8;
                bf16x8 va0 = *(const bf16x8*)&Kb[4096 + lq * 64 + vsl];
                acc0 = mfma32(va0, bf_.v, acc0);
                bf16x8 va1 = *(const bf16x8*)&Kb[4096 + (32 + lq) * 64 + vsl];
                acc1 = mfma32(va1, bf_.v, acc1);
            }
        }

        // ---- stage next chunk ----
        if (kb < 31) {
            __syncthreads();
            STAGE_WRITE(cur ^ 1);
            if (kb < 30) STAGE_LOAD(kb + 2);
            __syncthreads();
        }
    }

    // ---- finalize (lane-local; pair-sum for denominator) ----
    lsum += __shfl_xor(lsum, 32, 64);
    const float inv = 1.f / lsum;
    float* orow = out + ((size_t)(n & 1) * 2048 + qrow0) * 1024 + (n >> 1) * 64;
#pragma unroll
    for (int g = 0; g < 4; ++g) {
        f4v o0, o1;
#pragma unroll
        for (int rr = 0; rr < 4; ++rr) {
            o0[rr] = acc0[g * 4 + rr] * inv;
            o1[rr] = acc1[g * 4 + rr] * inv;
        }
        *(f4v*)&orow[g * 8 + 4 * hi] = o0;
        *(f4v*)&orow[32 + g * 8 + 4 * hi] = o1;
    }
#undef STAGE_LOAD
#undef STAGE_WRITE
}

// ---------------- launch ----------------
extern "C" void kernel_launch(void* const* d_in, const int* in_sizes, int n_in,
                              void* d_out, int out_size, void* d_ws, size_t ws_size,
                              hipStream_t stream) {
    (void)n_in; (void)out_size; (void)ws_size;
    const float* q  = (const float*)d_in[0];
    const float* k  = (const float*)d_in[1];
    const float* v  = (const float*)d_in[2];
    const float* Wq = (const float*)d_in[3];
    const float* Wk = (const float*)d_in[4];
    const float* Wv = (const float*)d_in[5];

    uint8_t* ws = (uint8_t*)d_ws;
    const size_t MB = 1024ull * 1024ull;
    u16* xq_hi = (u16*)(ws + 0 * MB);
    u16* xq_lo = (u16*)(ws + 8 * MB);
    u16* xk_hi = (u16*)(ws + 16 * MB);
    u16* xk_lo = (u16*)(ws + 24 * MB);
    u16* xv_hi = (u16*)(ws + 32 * MB);
    u16* xv_lo = (u16*)(ws + 40 * MB);
    u16* wq_f  = (u16*)(ws + 48 * MB);
    u16* wk_f  = (u16*)(ws + 50 * MB);
    u16* wv_f  = (u16*)(ws + 52 * MB);
    u16* qh    = (u16*)(ws + 54 * MB);
    u16* kh    = (u16*)(ws + 62 * MB);
    u16* vt    = (u16*)(ws + 70 * MB);

    PrepArgs pp;
    pp.src[0] = q;  pp.src[1] = k;  pp.src[2] = v;
    pp.src[3] = Wq; pp.src[4] = Wk; pp.src[5] = Wv;
    pp.hi[0] = xq_hi; pp.hi[1] = xk_hi; pp.hi[2] = xv_hi;
    pp.hi[3] = wq_f;  pp.hi[4] = wk_f;  pp.hi[5] = wv_f;
    pp.lo[0] = xq_lo; pp.lo[1] = xk_lo; pp.lo[2] = xv_lo;
    pp.lo[3] = nullptr; pp.lo[4] = nullptr; pp.lo[5] = nullptr;
    pp.n4[0] = pp.n4[1] = pp.n4[2] = in_sizes[0] / 4;
    pp.n4[3] = pp.n4[4] = pp.n4[5] = in_sizes[3] / 4;
    prep_kernel<<<dim3(2048, 6), 256, 0, stream>>>(pp);

    ProjArgs pa;
    pa.xhi[0] = xq_hi; pa.xhi[1] = xk_hi; pa.xhi[2] = xv_hi;
    pa.xlo[0] = xq_lo; pa.xlo[1] = xk_lo; pa.xlo[2] = xv_lo;
    pa.wf[0] = wq_f; pa.wf[1] = wk_f; pa.wf[2] = wv_f;
    pa.outq = qh; pa.outk = kh; pa.outvt = vt;
    proj_kernel<<<dim3(192), 512, 0, stream>>>(pa);

    attn_kernel<<<dim3(512), 256, 0, stream>>>(qh, kh, vt, (float*)d_out);
}

// Round 9
// 139.952 us; speedup vs baseline: 1.0094x; 1.0094x over previous
//
#include <hip/hip_runtime.h>
#include <hip/hip_bf16.h>
#include <stdint.h>

typedef unsigned short u16;
typedef __attribute__((ext_vector_type(8))) short bf16x8;
typedef __attribute__((ext_vector_type(8))) _Float16 f16x8;
typedef __attribute__((ext_vector_type(4))) float f32x4;
typedef __attribute__((ext_vector_type(16))) float f32x16;
typedef __attribute__((ext_vector_type(4))) u16 u16x4;
typedef __attribute__((ext_vector_type(4))) float f4v;

#define DEV __device__ __forceinline__

DEV u16 f2bf(float x) {
    union { float f; uint32_t u; } v; v.f = x;
    uint32_t r = v.u + 0x7FFF + ((v.u >> 16) & 1);
    return (u16)(r >> 16);
}

DEV float fexp2(float x) {
    float r;
    asm("v_exp_f32 %0, %1" : "=v"(r) : "v"(x));
    return r;
}

DEV f32x4 mfma16h(f16x8 a, f16x8 b, f32x4 c) {
    return __builtin_amdgcn_mfma_f32_16x16x32_f16(a, b, c, 0, 0, 0);
}
DEV f32x16 mfma32(bf16x8 a, bf16x8 b, f32x16 c) {
    return __builtin_amdgcn_mfma_f32_32x32x16_bf16(a, b, c, 0, 0, 0);
}

DEV void gld_lds16(const u16* g, u16* lds) {
    __builtin_amdgcn_global_load_lds(
        (const __attribute__((address_space(1))) void*)g,
        (__attribute__((address_space(3))) void*)lds, 16, 0, 0);
}

#define VMCNT2 asm volatile("s_waitcnt vmcnt(2)" ::: "memory")
#define VMCNT0 asm volatile("s_waitcnt vmcnt(0)" ::: "memory")
#define BAR() __builtin_amdgcn_s_barrier()

DEV u16 h2u(_Float16 h) { union { _Float16 h; u16 u; } v; v.h = h; return v.u; }

// ---------------- Pass A: fused X-split (fp16 hi/lo) + W-cast ----------------
struct PrepArgs {
    const float* src[6];
    u16* hi[6];
    u16* lo[6];   // null -> cast-only
    int n4[6];
};

__global__ __launch_bounds__(256) void prep_kernel(PrepArgs a) {
    const int z = blockIdx.y;
    const f4v* __restrict__ src = (const f4v*)a.src[z];
    u16x4* __restrict__ hi = (u16x4*)a.hi[z];
    u16x4* __restrict__ lo = (u16x4*)a.lo[z];
    const int n4 = a.n4[z];
    int i = blockIdx.x * blockDim.x + threadIdx.x;
    const int stride = gridDim.x * blockDim.x;
    if (lo) {
        for (; i < n4; i += stride) {
            f4v x = src[i];
            u16x4 h, l;
#pragma unroll
            for (int c = 0; c < 4; ++c) {
                float xv = x[c];
                _Float16 hb = (_Float16)xv;
                float r = xv - (float)hb;
                h[c] = h2u(hb);
                l[c] = h2u((_Float16)r);
            }
            hi[i] = h;
            lo[i] = l;
        }
    } else {
        for (; i < n4; i += stride) {
            f4v x = src[i];
            u16x4 d;
#pragma unroll
            for (int c = 0; c < 4; ++c) d[c] = h2u((_Float16)x[c]);
            hi[i] = d;
        }
    }
}

// ---------------- Pass B: projections — 256x256 tile, 8-wave, 8-phase ----------------
struct ProjArgs {
    const u16* xhi[3];
    const u16* xlo[3];
    const u16* wf[3];
    u16* outq;
    u16* outk;
    u16* outvt;
};

__global__ __launch_bounds__(512, 2) void proj_kernel(ProjArgs args) {
    __shared__ u16 lds[2][32768];

    const int tid = threadIdx.x;
    const int w = tid >> 6, l = tid & 63;
    const int fr = l & 15, fg = l >> 4;
    const int wa = w >> 2, wb = w & 3;

    const int b0 = blockIdx.x;
    const int swz = (b0 & 7) * 24 + (b0 >> 3);
    const int z = swz >> 6;
    const int r = swz & 63;

    int ta, tb;
    const u16 *A0, *A1, *B0, *B1;
    if (z < 2) {
        ta = r & 3; tb = r >> 2;
        A0 = args.wf[z]; A1 = args.wf[z];
        B0 = args.xhi[z]; B1 = args.xlo[z];
    } else {
        ta = r >> 2; tb = r & 3;
        A0 = args.xhi[2]; A1 = args.xlo[2];
        B0 = args.wf[2]; B1 = args.wf[2];
    }

    const int s_r = tid >> 3;
    const int s_c = (((tid & 7) ^ (s_r & 7)) << 3);
    const size_t aoff = (size_t)(ta * 256 + s_r) * 1024 + s_c;
    const size_t boff = (size_t)(tb * 256 + s_r) * 1024 + s_c;

    const int abase = (wa * 128 + fr) * 64;
    const int bbase = 16384 + (wb * 64 + fr) * 64;
    const int sl0 = ((fg) ^ (fr & 7)) << 3;
    const int sl1 = ((4 + fg) ^ (fr & 7)) << 3;

    f32x4 acc[8][4];
#pragma unroll
    for (int mi = 0; mi < 8; ++mi)
#pragma unroll
        for (int ni = 0; ni < 4; ++ni)
            acc[mi][ni] = (f32x4){0.f, 0.f, 0.f, 0.f};

#define STAGE2(SRC, OFFBASE, REGION, HALF, BUFN, KTN)                               \
    do {                                                                            \
        _Pragma("unroll")                                                           \
        for (int j = 0; j < 2; ++j) {                                               \
            gld_lds16((SRC) + (OFFBASE) + (size_t)((HALF) * 128 + j * 64) * 1024    \
                           + (size_t)(KTN) * 64,                                    \
                      &lds[BUFN][(REGION) + (HALF) * 8192 + j * 4096 + w * 512]);   \
        }                                                                           \
    } while (0)

#pragma unroll
    for (int h = 0; h < 2; ++h) {
#pragma unroll
        for (int j = 0; j < 2; ++j) {
            gld_lds16(A0 + aoff + (size_t)(h * 128 + j * 64) * 1024,
                      &lds[0][h * 8192 + j * 4096 + w * 512]);
            gld_lds16(B0 + boff + (size_t)(h * 128 + j * 64) * 1024,
                      &lds[0][16384 + h * 8192 + j * 4096 + w * 512]);
        }
    }

#define PHASE(MQ0, STAGECALL)                                                       \
    do {                                                                            \
        if (more) STAGECALL;                                                        \
        f16x8 p00 = *(const f16x8*)&Lb[abase + (MQ0) * 1024 + sl0];                 \
        f16x8 p01 = *(const f16x8*)&Lb[abase + (MQ0) * 1024 + sl1];                 \
        f16x8 p10 = *(const f16x8*)&Lb[abase + (MQ0 + 1) * 1024 + sl0];             \
        f16x8 p11 = *(const f16x8*)&Lb[abase + (MQ0 + 1) * 1024 + sl1];             \
        BAR();                                                                      \
        __builtin_amdgcn_s_setprio(1);                                              \
        _Pragma("unroll")                                                           \
        for (int ni = 0; ni < 4; ++ni) {                                            \
            acc[MQ0][ni] = mfma16h(p00, Bf0[ni], acc[MQ0][ni]);                     \
            acc[MQ0][ni] = mfma16h(p01, Bf1[ni], acc[MQ0][ni]);                     \
            acc[MQ0 + 1][ni] = mfma16h(p10, Bf0[ni], acc[MQ0 + 1][ni]);             \
            acc[MQ0 + 1][ni] = mfma16h(p11, Bf1[ni], acc[MQ0 + 1][ni]);             \
        }                                                                           \
        __builtin_amdgcn_s_setprio(0);                                              \
        BAR();                                                                      \
    } while (0)

#pragma unroll 1
    for (int t = 0; t < 32; ++t) {
        const int buf = t & 1;
        const int nbuf = buf ^ 1;
        const int tn = t + 1;
        const bool more = (tn < 32);
        const int termn = tn >> 4;
        const int ktn = tn & 15;
        const u16* An = termn ? A1 : A0;
        const u16* Bn = termn ? B1 : B0;
        const u16* Lb = &lds[buf][0];

        f16x8 Bf0[4], Bf1[4];

        if (more) STAGE2(An, aoff, 0, 0, nbuf, ktn);
        if (more) { VMCNT2; } else { VMCNT0; }
        BAR();
        {
            f16x8 a00 = *(const f16x8*)&Lb[abase + sl0];
            f16x8 a01 = *(const f16x8*)&Lb[abase + sl1];
            f16x8 a10 = *(const f16x8*)&Lb[abase + 1024 + sl0];
            f16x8 a11 = *(const f16x8*)&Lb[abase + 1024 + sl1];
#pragma unroll
            for (int ni = 0; ni < 4; ++ni) {
                Bf0[ni] = *(const f16x8*)&Lb[bbase + ni * 1024 + sl0];
                Bf1[ni] = *(const f16x8*)&Lb[bbase + ni * 1024 + sl1];
            }
            BAR();
            __builtin_amdgcn_s_setprio(1);
#pragma unroll
            for (int ni = 0; ni < 4; ++ni) {
                acc[0][ni] = mfma16h(a00, Bf0[ni], acc[0][ni]);
                acc[0][ni] = mfma16h(a01, Bf1[ni], acc[0][ni]);
                acc[1][ni] = mfma16h(a10, Bf0[ni], acc[1][ni]);
                acc[1][ni] = mfma16h(a11, Bf1[ni], acc[1][ni]);
            }
            __builtin_amdgcn_s_setprio(0);
            BAR();
        }
        PHASE(2, STAGE2(An, aoff, 0, 1, nbuf, ktn));
        PHASE(4, STAGE2(Bn, boff, 16384, 0, nbuf, ktn));
        PHASE(6, STAGE2(Bn, boff, 16384, 1, nbuf, ktn));
    }
#undef PHASE
#undef STAGE2

    if (z < 2) {
        u16* outp = (z == 0) ? args.outq : args.outk;
#pragma unroll
        for (int mq = 0; mq < 8; ++mq) {
#pragma unroll
            for (int ni = 0; ni < 4; ++ni) {
                const int e0 = ta * 256 + wa * 128 + mq * 16 + fg * 4;
                const int m = tb * 256 + wb * 64 + ni * 16 + fr;
                const int n = (m >> 11) * 16 + (e0 >> 6);
                const int s = m & 2047;
                u16x4 pk;
#pragma unroll
                for (int rr = 0; rr < 4; ++rr) pk[rr] = f2bf(acc[mq][ni][rr]);
                *(u16x4*)&outp[((size_t)(n * 2048 + s)) * 64 + (e0 & 63)] = pk;
            }
        }
    } else {
        u16* outp = args.outvt;
#pragma unroll
        for (int mq = 0; mq < 8; ++mq) {
#pragma unroll
            for (int ni = 0; ni < 4; ++ni) {
                const int m0 = ta * 256 + wa * 128 + mq * 16 + fg * 4;
                const int e = tb * 256 + wb * 64 + ni * 16 + fr;
                const int n = (m0 >> 11) * 16 + (e >> 6);
                u16x4 pk;
#pragma unroll
                for (int rr = 0; rr < 4; ++rr) pk[rr] = f2bf(acc[mq][ni][rr]);
                *(u16x4*)&outp[((size_t)(n * 64 + (e & 63))) * 2048 + (m0 & 2047)] = pk;
            }
        }
    }
}

// ---------------- Pass C: flash attention, 32x32 MFMA + in-block KV-split ----------------
// 8 waves = 4 pairs; waves {w, w+4} share 32 q-rows, split keys 0..1023 / 1024..2047
// (independent online softmaxes, exact merge at end through LDS).
// Swapped QK^T + bit-2<->3 K-store permute => softmax and PV packing fully lane-local.
__global__ __launch_bounds__(512, 4) void attn_kernel(const u16* __restrict__ qh,
                                                      const u16* __restrict__ kh,
                                                      const u16* __restrict__ vt,
                                                      float* __restrict__ out) {
    __shared__ u16 lds[2][2][8192];   // [buf][group][ K 64x64 | V 64x64 ]

    const int tid = threadIdx.x;
    const int w = tid >> 6, l = tid & 63;
    const int hi = l >> 5, lq = l & 31;
    const int rot = lq & 7;
    const int g = w >> 2;      // key-half group
    const int pr = w & 3;      // pair index -> q subtile

    const int b = blockIdx.x;
    const int n = (b & 7) * 4 + ((b >> 3) >> 4);   // head-batch 0..31
    const int qt = (b >> 3) & 15;
    const int qrow0 = qt * 128 + pr * 32 + lq;
    const float cs = 0.125f * 1.44269504088896f;

    const u16* khn = kh + (size_t)n * 2048 * 64 + (size_t)g * 1024 * 64;
    const u16* vtg = vt + (size_t)n * 64 * 2048 + g * 1024;

    const u16* qrow = qh + ((size_t)n * 2048 + qrow0) * 64;
    bf16x8 qf[4];
#pragma unroll
    for (int f = 0; f < 4; ++f)
        qf[f] = *(const bf16x8*)(qrow + f * 16 + hi * 8);

    // ---- staging geometry (256 threads per group; 2 K-rows + 2 V-rows each) ----
    const int st = tid & 255;
    const int srow = st >> 3;           // 0..31
    const int sch = st & 7;
    const int pr0 = (srow & 19) | ((srow & 4) << 1) | ((srow & 8) >> 1);  // bits 2<->3
    const int kslot = ((sch + (pr0 & 7)) & 7) * 8;
    const int kw0 = pr0 * 64 + kslot;
    const int kw1 = (pr0 + 32) * 64 + kslot;
    const int vslot = ((sch + (srow & 7)) & 7) * 8;
    const int vw0 = 4096 + srow * 64 + vslot;
    const int vw1 = 4096 + (srow + 32) * 64 + vslot;

    f32x16 acc0, acc1;
#pragma unroll
    for (int rr = 0; rr < 16; ++rr) { acc0[rr] = 0.f; acc1[rr] = 0.f; }
    float mrun = -INFINITY;
    float lsum = 0.f;

    bf16x8 kr0, kr1, vr0, vr1;

#define STAGE_LOAD(c_) do {                                                          \
        kr0 = *(const bf16x8*)(khn + (size_t)((c_) * 64 + srow) * 64 + sch * 8);     \
        kr1 = *(const bf16x8*)(khn + (size_t)((c_) * 64 + srow + 32) * 64 + sch * 8);\
        vr0 = *(const bf16x8*)(vtg + (size_t)srow * 2048 + (c_) * 64 + sch * 8);     \
        vr1 = *(const bf16x8*)(vtg + (size_t)(srow + 32) * 2048 + (c_) * 64 + sch * 8);\
    } while (0)

#define STAGE_WRITE(buf_) do {                                                       \
        u16* p_ = &lds[buf_][g][0];                                                  \
        *(bf16x8*)&p_[kw0] = kr0;                                                    \
        *(bf16x8*)&p_[kw1] = kr1;                                                    \
        *(bf16x8*)&p_[vw0] = vr0;                                                    \
        *(bf16x8*)&p_[vw1] = vr1;                                                    \
    } while (0)

    STAGE_LOAD(0);
    STAGE_WRITE(0);
    STAGE_LOAD(1);
    __syncthreads();

    for (int c = 0; c < 16; ++c) {
        const int cur = c & 1;
        const u16* Kb = &lds[cur][g][0];

        // ---- QK^T (swapped): sf0 = keys 0..31, sf1 = keys 32..63 (permuted rows) ----
        f32x16 sf0, sf1;
#pragma unroll
        for (int rr = 0; rr < 16; ++rr) { sf0[rr] = 0.f; sf1[rr] = 0.f; }
#pragma unroll
        for (int f = 0; f < 4; ++f) {
            bf16x8 a0 = *(const bf16x8*)&Kb[lq * 64 + ((2 * f + hi + rot) & 7) * 8];
            sf0 = mfma32(a0, qf[f], sf0);
        }
#pragma unroll
        for (int f = 0; f < 4; ++f) {
            bf16x8 a1 = *(const bf16x8*)&Kb[2048 + lq * 64 + ((2 * f + hi + rot) & 7) * 8];
            sf1 = mfma32(a1, qf[f], sf1);
        }

        // ---- row max ----
        float t8[8];
#pragma unroll
        for (int i = 0; i < 8; ++i)
            t8[i] = fmaxf(fmaxf(sf0[2 * i], sf0[2 * i + 1]),
                          fmaxf(sf1[2 * i], sf1[2 * i + 1]));
        float cm = fmaxf(fmaxf(fmaxf(t8[0], t8[1]), fmaxf(t8[2], t8[3])),
                         fmaxf(fmaxf(t8[4], t8[5]), fmaxf(t8[6], t8[7])));
        cm = fmaxf(cm, __shfl_xor(cm, 32, 64));

        if (__any(cm > mrun)) {
            float mnew = fmaxf(mrun, cm);
            float sc = fexp2(cs * (mrun - mnew));
            mrun = mnew;
            lsum *= sc;
#pragma unroll
            for (int rr = 0; rr < 16; ++rr) { acc0[rr] *= sc; acc1[rr] *= sc; }
        }

        // ---- p = exp2(cs*s - cs*m) ----
        const float negm = -cs * mrun;
#pragma unroll
        for (int rr = 0; rr < 16; ++rr) {
            sf0[rr] = fexp2(fmaf(cs, sf0[rr], negm));
            sf1[rr] = fexp2(fmaf(cs, sf1[rr], negm));
            lsum += sf0[rr] + sf1[rr];
        }

        // ---- PV: B-frag = own regs, keys match V's natural order ----
#pragma unroll
        for (int ks = 0; ks < 2; ++ks) {
#pragma unroll
            for (int W = 0; W < 2; ++W) {
                union { bf16x8 v; uint32_t u[4]; } bf_;
#pragma unroll
                for (int j2 = 0; j2 < 4; ++j2) {
                    float lo = ks ? sf1[W * 8 + 2 * j2] : sf0[W * 8 + 2 * j2];
                    float hv = ks ? sf1[W * 8 + 2 * j2 + 1] : sf0[W * 8 + 2 * j2 + 1];
                    asm("v_cvt_pk_bf16_f32 %0, %1, %2" : "=v"(bf_.u[j2]) : "v"(lo), "v"(hv));
                }
                const int s2 = ks * 2 + W;
                const int vsl = ((2 * s2 + hi + rot) & 7) * 8;
                bf16x8 va0 = *(const bf16x8*)&Kb[4096 + lq * 64 + vsl];
                acc0 = mfma32(va0, bf_.v, acc0);
                bf16x8 va1 = *(const bf16x8*)&Kb[4096 + (32 + lq) * 64 + vsl];
                acc1 = mfma32(va1, bf_.v, acc1);
            }
        }

        if (c < 15) {
            __syncthreads();
            STAGE_WRITE(cur ^ 1);
            if (c < 14) STAGE_LOAD(c + 2);
            __syncthreads();
        }
    }

    // ---- pair merge (exact): high group publishes, low group combines ----
    lsum += __shfl_xor(lsum, 32, 64);

    __syncthreads();
    float* lf = (float*)&lds[0][0][0];
    const int mbase = pr * 2048 + l * 32;
    if (g == 1) {
#pragma unroll
        for (int q_ = 0; q_ < 8; ++q_) {
            const int slot = ((q_ + l) & 7) * 4;
            f4v tv;
#pragma unroll
            for (int rr = 0; rr < 4; ++rr)
                tv[rr] = (q_ < 4) ? acc0[(q_ & 3) * 4 + rr] : acc1[(q_ & 3) * 4 + rr];
            *(f4v*)&lf[mbase + slot] = tv;   // NOTE: slot encodes quad via ((q+l)&7)
        }
        lf[8192 + pr * 128 + l * 2] = mrun;
        lf[8192 + pr * 128 + l * 2 + 1] = lsum;
    }
    __syncthreads();
    if (g == 0) {
        const float Bm = lf[8192 + pr * 128 + l * 2];
        const float Bl = lf[8192 + pr * 128 + l * 2 + 1];
        const float mf = fmaxf(mrun, Bm);
        const float aA = fexp2(cs * (mrun - mf));
        const float aB = fexp2(cs * (Bm - mf));
        const float inv = 1.f / (lsum * aA + Bl * aB);

        float* orow = out + ((size_t)(n & 1) * 2048 + qrow0) * 1024 + (n >> 1) * 64;
#pragma unroll
        for (int q_ = 0; q_ < 8; ++q_) {
            const int slot = ((q_ + l) & 7) * 4;
            f4v bv = *(const f4v*)&lf[mbase + slot];
            f4v o;
#pragma unroll
            for (int rr = 0; rr < 4; ++rr) {
                float av = (q_ < 4) ? acc0[(q_ & 3) * 4 + rr] : acc1[(q_ & 3) * 4 + rr];
                o[rr] = (av * aA + bv[rr] * aB) * inv;
            }
            const int dbase = (q_ < 4) ? ((q_ & 3) * 8 + 4 * hi) : (32 + (q_ & 3) * 8 + 4 * hi);
            *(f4v*)&orow[dbase] = o;
        }
    }
#undef STAGE_LOAD
#undef STAGE_WRITE
}

// ---------------- launch ----------------
extern "C" void kernel_launch(void* const* d_in, const int* in_sizes, int n_in,
                              void* d_out, int out_size, void* d_ws, size_t ws_size,
                              hipStream_t stream) {
    (void)n_in; (void)out_size; (void)ws_size;
    const float* q  = (const float*)d_in[0];
    const float* k  = (const float*)d_in[1];
    const float* v  = (const float*)d_in[2];
    const float* Wq = (const float*)d_in[3];
    const float* Wk = (const float*)d_in[4];
    const float* Wv = (const float*)d_in[5];

    uint8_t* ws = (uint8_t*)d_ws;
    const size_t MB = 1024ull * 1024ull;
    u16* xq_hi = (u16*)(ws + 0 * MB);
    u16* xq_lo = (u16*)(ws + 8 * MB);
    u16* xk_hi = (u16*)(ws + 16 * MB);
    u16* xk_lo = (u16*)(ws + 24 * MB);
    u16* xv_hi = (u16*)(ws + 32 * MB);
    u16* xv_lo = (u16*)(ws + 40 * MB);
    u16* wq_f  = (u16*)(ws + 48 * MB);
    u16* wk_f  = (u16*)(ws + 50 * MB);
    u16* wv_f  = (u16*)(ws + 52 * MB);
    u16* qh    = (u16*)(ws + 54 * MB);
    u16* kh    = (u16*)(ws + 62 * MB);
    u16* vt    = (u16*)(ws + 70 * MB);

    PrepArgs pp;
    pp.src[0] = q;  pp.src[1] = k;  pp.src[2] = v;
    pp.src[3] = Wq; pp.src[4] = Wk; pp.src[5] = Wv;
    pp.hi[0] = xq_hi; pp.hi[1] = xk_hi; pp.hi[2] = xv_hi;
    pp.hi[3] = wq_f;  pp.hi[4] = wk_f;  pp.hi[5] = wv_f;
    pp.lo[0] = xq_lo; pp.lo[1] = xk_lo; pp.lo[2] = xv_lo;
    pp.lo[3] = nullptr; pp.lo[4] = nullptr; pp.lo[5] = nullptr;
    pp.n4[0] = pp.n4[1] = pp.n4[2] = in_sizes[0] / 4;
    pp.n4[3] = pp.n4[4] = pp.n4[5] = in_sizes[3] / 4;
    prep_kernel<<<dim3(2048, 6), 256, 0, stream>>>(pp);

    ProjArgs pa;
    pa.xhi[0] = xq_hi; pa.xhi[1] = xk_hi; pa.xhi[2] = xv_hi;
    pa.xlo[0] = xq_lo; pa.xlo[1] = xk_lo; pa.xlo[2] = xv_lo;
    pa.wf[0] = wq_f; pa.wf[1] = wk_f; pa.wf[2] = wv_f;
    pa.outq = qh; pa.outk = kh; pa.outvt = vt;
    proj_kernel<<<dim3(192), 512, 0, stream>>>(pa);

    attn_kernel<<<dim3(512), 512, 0, stream>>>(qh, kh, vt, (float*)d_out);
}

// Round 10
// 103.727 us; speedup vs baseline: 1.3619x; 1.3492x over previous
//
#include <hip/hip_runtime.h>
#include <hip/hip_bf16.h>
#include <stdint.h>

typedef unsigned short u16;
typedef __attribute__((ext_vector_type(8))) short bf16x8;
typedef __attribute__((ext_vector_type(8))) _Float16 f16x8;
typedef __attribute__((ext_vector_type(4))) float f32x4;
typedef __attribute__((ext_vector_type(4))) u16 u16x4;
typedef __attribute__((ext_vector_type(4))) float f4v;

#define DEV __device__ __forceinline__

DEV u16 f2bf(float x) {
    union { float f; uint32_t u; } v; v.f = x;
    uint32_t r = v.u + 0x7FFF + ((v.u >> 16) & 1);
    return (u16)(r >> 16);
}

DEV float fexp2(float x) {
    float r;
    asm("v_exp_f32 %0, %1" : "=v"(r) : "v"(x));
    return r;
}

DEV f32x4 mfma16(bf16x8 a, bf16x8 b, f32x4 c) {
    return __builtin_amdgcn_mfma_f32_16x16x32_bf16(a, b, c, 0, 0, 0);
}
DEV f32x4 mfma16h(f16x8 a, f16x8 b, f32x4 c) {
    return __builtin_amdgcn_mfma_f32_16x16x32_f16(a, b, c, 0, 0, 0);
}

DEV void gld_lds16(const u16* g, u16* lds) {
    __builtin_amdgcn_global_load_lds(
        (const __attribute__((address_space(1))) void*)g,
        (__attribute__((address_space(3))) void*)lds, 16, 0, 0);
}

#define VMCNT2 asm volatile("s_waitcnt vmcnt(2)" ::: "memory")
#define VMCNT0 asm volatile("s_waitcnt vmcnt(0)" ::: "memory")
#define BAR() __builtin_amdgcn_s_barrier()

DEV u16 h2u(_Float16 h) { union { _Float16 h; u16 u; } v; v.h = h; return v.u; }

// ---------------- Pass A: fp32 -> fp16 cast (X and W) ----------------
struct PrepArgs {
    const float* src[6];
    u16* dst[6];
    int n4[6];
};

__global__ __launch_bounds__(256) void prep_kernel(PrepArgs a) {
    const int z = blockIdx.y;
    const f4v* __restrict__ src = (const f4v*)a.src[z];
    u16x4* __restrict__ dst = (u16x4*)a.dst[z];
    const int n4 = a.n4[z];
    int i = blockIdx.x * blockDim.x + threadIdx.x;
    const int stride = gridDim.x * blockDim.x;
    for (; i < n4; i += stride) {
        f4v x = src[i];
        u16x4 d;
#pragma unroll
        for (int c = 0; c < 4; ++c) d[c] = h2u((_Float16)x[c]);
        dst[i] = d;
    }
}

// ---------------- Pass B: projections — 256x256 tile, 8-wave, 8-phase, fp16 1-term ----------------
// D[a][b] = sum_d A[a][d]*B[b][d], both row-major [rows][1024] fp16, 16 K-tiles.
// z<2 : A = Wf (1024 rows, output-e), B = Xf -> qh/kh [n][s][dk] (bf16)
// z==2: A = Xf (4096 rows, output-m), B = Wf -> vt [n][dk][s] (bf16)
struct ProjArgs {
    const u16* xf[3];
    const u16* wf[3];
    u16* outq;
    u16* outk;
    u16* outvt;
};

__global__ __launch_bounds__(512, 2) void proj_kernel(ProjArgs args) {
    __shared__ u16 lds[2][32768];

    const int tid = threadIdx.x;
    const int w = tid >> 6, l = tid & 63;
    const int fr = l & 15, fg = l >> 4;
    const int wa = w >> 2, wb = w & 3;

    const int b0 = blockIdx.x;
    const int swz = (b0 & 7) * 24 + (b0 >> 3);
    const int z = swz >> 6;
    const int r = swz & 63;

    int ta, tb;
    const u16 *A0, *B0;
    if (z < 2) {
        ta = r & 3; tb = r >> 2;
        A0 = args.wf[z];
        B0 = args.xf[z];
    } else {
        ta = r >> 2; tb = r & 3;
        A0 = args.xf[2];
        B0 = args.wf[2];
    }

    const int s_r = tid >> 3;
    const int s_c = (((tid & 7) ^ (s_r & 7)) << 3);
    const size_t aoff = (size_t)(ta * 256 + s_r) * 1024 + s_c;
    const size_t boff = (size_t)(tb * 256 + s_r) * 1024 + s_c;

    const int abase = (wa * 128 + fr) * 64;
    const int bbase = 16384 + (wb * 64 + fr) * 64;
    const int sl0 = ((fg) ^ (fr & 7)) << 3;
    const int sl1 = ((4 + fg) ^ (fr & 7)) << 3;

    f32x4 acc[8][4];
#pragma unroll
    for (int mi = 0; mi < 8; ++mi)
#pragma unroll
        for (int ni = 0; ni < 4; ++ni)
            acc[mi][ni] = (f32x4){0.f, 0.f, 0.f, 0.f};

#define STAGE2(SRC, OFFBASE, REGION, HALF, BUFN, KTN)                               \
    do {                                                                            \
        _Pragma("unroll")                                                           \
        for (int j = 0; j < 2; ++j) {                                               \
            gld_lds16((SRC) + (OFFBASE) + (size_t)((HALF) * 128 + j * 64) * 1024    \
                           + (size_t)(KTN) * 64,                                    \
                      &lds[BUFN][(REGION) + (HALF) * 8192 + j * 4096 + w * 512]);   \
        }                                                                           \
    } while (0)

#pragma unroll
    for (int h = 0; h < 2; ++h) {
#pragma unroll
        for (int j = 0; j < 2; ++j) {
            gld_lds16(A0 + aoff + (size_t)(h * 128 + j * 64) * 1024,
                      &lds[0][h * 8192 + j * 4096 + w * 512]);
            gld_lds16(B0 + boff + (size_t)(h * 128 + j * 64) * 1024,
                      &lds[0][16384 + h * 8192 + j * 4096 + w * 512]);
        }
    }

#define PHASE(MQ0, STAGECALL)                                                       \
    do {                                                                            \
        if (more) STAGECALL;                                                        \
        f16x8 p00 = *(const f16x8*)&Lb[abase + (MQ0) * 1024 + sl0];                 \
        f16x8 p01 = *(const f16x8*)&Lb[abase + (MQ0) * 1024 + sl1];                 \
        f16x8 p10 = *(const f16x8*)&Lb[abase + (MQ0 + 1) * 1024 + sl0];             \
        f16x8 p11 = *(const f16x8*)&Lb[abase + (MQ0 + 1) * 1024 + sl1];             \
        BAR();                                                                      \
        __builtin_amdgcn_s_setprio(1);                                              \
        _Pragma("unroll")                                                           \
        for (int ni = 0; ni < 4; ++ni) {                                            \
            acc[MQ0][ni] = mfma16h(p00, Bf0[ni], acc[MQ0][ni]);                     \
            acc[MQ0][ni] = mfma16h(p01, Bf1[ni], acc[MQ0][ni]);                     \
            acc[MQ0 + 1][ni] = mfma16h(p10, Bf0[ni], acc[MQ0 + 1][ni]);             \
            acc[MQ0 + 1][ni] = mfma16h(p11, Bf1[ni], acc[MQ0 + 1][ni]);             \
        }                                                                           \
        __builtin_amdgcn_s_setprio(0);                                              \
        BAR();                                                                      \
    } while (0)

#pragma unroll 1
    for (int t = 0; t < 16; ++t) {
        const int buf = t & 1;
        const int nbuf = buf ^ 1;
        const int tn = t + 1;
        const bool more = (tn < 16);
        const int ktn = tn;
        const u16* An = A0;
        const u16* Bn = B0;
        const u16* Lb = &lds[buf][0];

        f16x8 Bf0[4], Bf1[4];

        if (more) STAGE2(An, aoff, 0, 0, nbuf, ktn);
        if (more) { VMCNT2; } else { VMCNT0; }
        BAR();
        {
            f16x8 a00 = *(const f16x8*)&Lb[abase + sl0];
            f16x8 a01 = *(const f16x8*)&Lb[abase + sl1];
            f16x8 a10 = *(const f16x8*)&Lb[abase + 1024 + sl0];
            f16x8 a11 = *(const f16x8*)&Lb[abase + 1024 + sl1];
#pragma unroll
            for (int ni = 0; ni < 4; ++ni) {
                Bf0[ni] = *(const f16x8*)&Lb[bbase + ni * 1024 + sl0];
                Bf1[ni] = *(const f16x8*)&Lb[bbase + ni * 1024 + sl1];
            }
            BAR();
            __builtin_amdgcn_s_setprio(1);
#pragma unroll
            for (int ni = 0; ni < 4; ++ni) {
                acc[0][ni] = mfma16h(a00, Bf0[ni], acc[0][ni]);
                acc[0][ni] = mfma16h(a01, Bf1[ni], acc[0][ni]);
                acc[1][ni] = mfma16h(a10, Bf0[ni], acc[1][ni]);
                acc[1][ni] = mfma16h(a11, Bf1[ni], acc[1][ni]);
            }
            __builtin_amdgcn_s_setprio(0);
            BAR();
        }
        PHASE(2, STAGE2(An, aoff, 0, 1, nbuf, ktn));
        PHASE(4, STAGE2(Bn, boff, 16384, 0, nbuf, ktn));
        PHASE(6, STAGE2(Bn, boff, 16384, 1, nbuf, ktn));
    }
#undef PHASE
#undef STAGE2

    if (z < 2) {
        u16* outp = (z == 0) ? args.outq : args.outk;
#pragma unroll
        for (int mq = 0; mq < 8; ++mq) {
#pragma unroll
            for (int ni = 0; ni < 4; ++ni) {
                const int e0 = ta * 256 + wa * 128 + mq * 16 + fg * 4;
                const int m = tb * 256 + wb * 64 + ni * 16 + fr;
                const int n = (m >> 11) * 16 + (e0 >> 6);
                const int s = m & 2047;
                u16x4 pk;
#pragma unroll
                for (int rr = 0; rr < 4; ++rr) pk[rr] = f2bf(acc[mq][ni][rr]);
                *(u16x4*)&outp[((size_t)(n * 2048 + s)) * 64 + (e0 & 63)] = pk;
            }
        }
    } else {
        u16* outp = args.outvt;
#pragma unroll
        for (int mq = 0; mq < 8; ++mq) {
#pragma unroll
            for (int ni = 0; ni < 4; ++ni) {
                const int m0 = ta * 256 + wa * 128 + mq * 16 + fg * 4;
                const int e = tb * 256 + wb * 64 + ni * 16 + fr;
                const int n = (m0 >> 11) * 16 + (e >> 6);
                u16x4 pk;
#pragma unroll
                for (int rr = 0; rr < 4; ++rr) pk[rr] = f2bf(acc[mq][ni][rr]);
                *(u16x4*)&outp[((size_t)(n * 64 + (e & 63))) * 2048 + (m0 & 2047)] = pk;
            }
        }
    }
}

// ---------------- Pass C: flash attention (round-6 version) ----------------
// Swapped QK^T (softmax lane-local) AND swapped PV (acc^T: col=q=lane&15), so
// rescale/1-over-l are lane-local. Row-sum via all-ones A-frag MFMA.
__global__ __launch_bounds__(512, 4) void attn_kernel(const u16* __restrict__ qh,
                                                      const u16* __restrict__ kh,
                                                      const u16* __restrict__ vt,
                                                      float* __restrict__ out) {
    __shared__ u16 lds[2][16384];

    const int tid = threadIdx.x;
    const int w = tid >> 6, l = tid & 63;
    const int fr = l & 15, fg = l >> 4;

    const int b = blockIdx.x;
    const int n = (b & 7) * 4 + ((b >> 3) >> 4);
    const int qt = (b >> 3) & 15;
    const int qbase = qt * 128 + w * 16;
    const float cs = 0.125f * 1.44269504088896f;

    const u16* khn = kh + (size_t)n * 2048 * 64;
    const u16* vtn = vt + (size_t)n * 64 * 2048;

    const u16* qrow = qh + ((size_t)n * 2048 + qbase + fr) * 64;
    bf16x8 aq0 = *(const bf16x8*)(qrow + fg * 8);
    bf16x8 aq1 = *(const bf16x8*)(qrow + 32 + fg * 8);

    bf16x8 ones;
#pragma unroll
    for (int j = 0; j < 8; ++j) ones[j] = (short)0x3F80;

    const int krow_s = tid >> 2;
    const int kcol_s = (tid & 3) * 16;
    const int kg_s = ((tid >> 2) & 3) + 4 * ((tid >> 5) & 1);
    const int kws0 = ((((tid & 3) * 2 + 0) + kg_s) & 7) * 8;
    const int kws1 = ((((tid & 3) * 2 + 1) + kg_s) & 7) * 8;
    const int vrow_s = tid >> 3;
    const int vcol_s = (tid & 7) * 16;
    const int vg_s = (tid >> 3) & 7;
    const int vws0 = ((((tid & 7) * 2 + 0) + vg_s) & 15) * 8;
    const int vws1 = ((((tid & 7) * 2 + 1) + vg_s) & 15) * 8;

    const int rbase = ((fr >> 2) << 3) + (fr & 3);
    const int kg_r = (fr & 3) + 4 * ((fr >> 2) & 1);
    const int ksl0 = (((fg + 0) + kg_r) & 7) * 8;
    const int ksl1 = (((fg + 4) + kg_r) & 7) * 8;
    const int vg_r = fr & 7;

    f32x4 acc[5];
#pragma unroll
    for (int dc = 0; dc < 5; ++dc) acc[dc] = (f32x4){0.f, 0.f, 0.f, 0.f};
    float mrun = -INFINITY;

    bf16x8 kr0, kr1, vr0, vr1;

#define STAGE_LOAD(kb_) do {                                                       \
        const u16* ksrc = khn + ((size_t)((kb_) * 128 + krow_s)) * 64 + kcol_s;    \
        kr0 = *(const bf16x8*)(ksrc);                                              \
        kr1 = *(const bf16x8*)(ksrc + 8);                                          \
        const u16* vsrc = vtn + (size_t)vrow_s * 2048 + (kb_) * 128 + vcol_s;      \
        vr0 = *(const bf16x8*)(vsrc);                                              \
        vr1 = *(const bf16x8*)(vsrc + 8);                                          \
    } while (0)

#define STAGE_WRITE(buf_) do {                                                     \
        u16* kp = &lds[buf_][0];                                                   \
        *(bf16x8*)&kp[krow_s * 64 + kws0] = kr0;                                   \
        *(bf16x8*)&kp[krow_s * 64 + kws1] = kr1;                                   \
        u16* vp = &lds[buf_][8192];                                                \
        *(bf16x8*)&vp[vrow_s * 128 + vws0] = vr0;                                  \
        *(bf16x8*)&vp[vrow_s * 128 + vws1] = vr1;                                  \
    } while (0)

    STAGE_LOAD(0);
    STAGE_WRITE(0);
    STAGE_LOAD(1);
    __syncthreads();

    for (int kb = 0; kb < 16; ++kb) {
        const int cur = kb & 1;
        const u16* Kb = &lds[cur][0];
        const u16* Vb = &lds[cur][8192];

        f32x4 sf[8];
#pragma unroll
        for (int c = 0; c < 8; ++c) {
            const int rr = ((c >> 1) << 5) + ((c & 1) << 2) + rbase;
            f32x4 s = (f32x4){0.f, 0.f, 0.f, 0.f};
            s = mfma16(*(const bf16x8*)&Kb[rr * 64 + ksl0], aq0, s);
            s = mfma16(*(const bf16x8*)&Kb[rr * 64 + ksl1], aq1, s);
            sf[c] = s;
        }

        f32x4 cmv = sf[0];
#pragma unroll
        for (int c = 1; c < 8; ++c)
#pragma unroll
            for (int rr = 0; rr < 4; ++rr) cmv[rr] = fmaxf(cmv[rr], sf[c][rr]);
        float cm = fmaxf(fmaxf(cmv[0], cmv[1]), fmaxf(cmv[2], cmv[3]));
        cm = fmaxf(cm, __shfl_xor(cm, 16, 64));
        cm = fmaxf(cm, __shfl_xor(cm, 32, 64));

        if (__any(cm > mrun)) {
            float mnew = fmaxf(mrun, cm);
            float sc = fexp2(cs * (mrun - mnew));
            mrun = mnew;
#pragma unroll
            for (int dc = 0; dc < 5; ++dc)
#pragma unroll
                for (int rr = 0; rr < 4; ++rr) acc[dc][rr] *= sc;
        }

        const float negm = -cs * mrun;
#pragma unroll
        for (int c = 0; c < 8; ++c) {
#pragma unroll
            for (int rr = 0; rr < 4; ++rr)
                sf[c][rr] = fexp2(fmaf(cs, sf[c][rr], negm));
        }

#pragma unroll
        for (int pw = 0; pw < 4; ++pw) {
            union { bf16x8 v; uint32_t u[4]; } ap;
#pragma unroll
            for (int q2 = 0; q2 < 4; ++q2) {
                float lo = sf[2 * pw + (q2 >> 1)][(q2 & 1) * 2 + 0];
                float hi = sf[2 * pw + (q2 >> 1)][(q2 & 1) * 2 + 1];
                asm("v_cvt_pk_bf16_f32 %0, %1, %2" : "=v"(ap.u[q2]) : "v"(lo), "v"(hi));
            }
#pragma unroll
            for (int dc = 0; dc < 4; ++dc) {
                const int vsl = (((pw * 4 + fg) + vg_r) & 15) * 8;
                acc[dc] = mfma16(*(const bf16x8*)&Vb[(dc * 16 + fr) * 128 + vsl],
                                 ap.v, acc[dc]);
            }
            acc[4] = mfma16(ones, ap.v, acc[4]);
        }

        if (kb < 15) {
            __syncthreads();
            STAGE_WRITE(cur ^ 1);
            if (kb < 14) STAGE_LOAD(kb + 2);
            __syncthreads();
        }
    }

    const float inv = 1.f / acc[4][0];
    const int bq = n & 1;
    const int col0 = (n >> 1) * 64;
    float* orow = out + ((size_t)bq * 2048 + qbase + fr) * 1024 + col0 + fg * 4;
#pragma unroll
    for (int dblk = 0; dblk < 4; ++dblk) {
        f4v o;
#pragma unroll
        for (int rr = 0; rr < 4; ++rr) o[rr] = acc[dblk][rr] * inv;
        *(f4v*)&orow[dblk * 16] = o;
    }
#undef STAGE_LOAD
#undef STAGE_WRITE
}

// ---------------- launch ----------------
extern "C" void kernel_launch(void* const* d_in, const int* in_sizes, int n_in,
                              void* d_out, int out_size, void* d_ws, size_t ws_size,
                              hipStream_t stream) {
    (void)n_in; (void)out_size; (void)ws_size;
    const float* q  = (const float*)d_in[0];
    const float* k  = (const float*)d_in[1];
    const float* v  = (const float*)d_in[2];
    const float* Wq = (const float*)d_in[3];
    const float* Wk = (const float*)d_in[4];
    const float* Wv = (const float*)d_in[5];

    uint8_t* ws = (uint8_t*)d_ws;
    const size_t MB = 1024ull * 1024ull;
    u16* xq_f = (u16*)(ws + 0 * MB);
    u16* xk_f = (u16*)(ws + 8 * MB);
    u16* xv_f = (u16*)(ws + 16 * MB);
    u16* wq_f = (u16*)(ws + 24 * MB);
    u16* wk_f = (u16*)(ws + 26 * MB);
    u16* wv_f = (u16*)(ws + 28 * MB);
    u16* qh   = (u16*)(ws + 30 * MB);
    u16* kh   = (u16*)(ws + 38 * MB);
    u16* vt   = (u16*)(ws + 46 * MB);

    PrepArgs pp;
    pp.src[0] = q;  pp.src[1] = k;  pp.src[2] = v;
    pp.src[3] = Wq; pp.src[4] = Wk; pp.src[5] = Wv;
    pp.dst[0] = xq_f; pp.dst[1] = xk_f; pp.dst[2] = xv_f;
    pp.dst[3] = wq_f; pp.dst[4] = wk_f; pp.dst[5] = wv_f;
    pp.n4[0] = pp.n4[1] = pp.n4[2] = in_sizes[0] / 4;
    pp.n4[3] = pp.n4[4] = pp.n4[5] = in_sizes[3] / 4;
    prep_kernel<<<dim3(1024, 6), 256, 0, stream>>>(pp);

    ProjArgs pa;
    pa.xf[0] = xq_f; pa.xf[1] = xk_f; pa.xf[2] = xv_f;
    pa.wf[0] = wq_f; pa.wf[1] = wk_f; pa.wf[2] = wv_f;
    pa.outq = qh; pa.outk = kh; pa.outvt = vt;
    proj_kernel<<<dim3(192), 512, 0, stream>>>(pa);

    attn_kernel<<<dim3(512), 512, 0, stream>>>(qh, kh, vt, (float*)d_out);
}

// Round 11
// 102.445 us; speedup vs baseline: 1.3790x; 1.0125x over previous
//
#include <hip/hip_runtime.h>
#include <hip/hip_bf16.h>
#include <stdint.h>

typedef unsigned short u16;
typedef __attribute__((ext_vector_type(8))) short bf16x8;
typedef __attribute__((ext_vector_type(8))) _Float16 f16x8;
typedef __attribute__((ext_vector_type(4))) float f32x4;
typedef __attribute__((ext_vector_type(4))) u16 u16x4;
typedef __attribute__((ext_vector_type(4))) float f4v;

#define DEV __device__ __forceinline__

DEV u16 f2bf(float x) {
    union { float f; uint32_t u; } v; v.f = x;
    uint32_t r = v.u + 0x7FFF + ((v.u >> 16) & 1);
    return (u16)(r >> 16);
}

DEV float fexp2(float x) {
    float r;
    asm("v_exp_f32 %0, %1" : "=v"(r) : "v"(x));
    return r;
}

DEV f32x4 mfma16(bf16x8 a, bf16x8 b, f32x4 c) {
    return __builtin_amdgcn_mfma_f32_16x16x32_bf16(a, b, c, 0, 0, 0);
}
DEV f32x4 mfma16h(f16x8 a, f16x8 b, f32x4 c) {
    return __builtin_amdgcn_mfma_f32_16x16x32_f16(a, b, c, 0, 0, 0);
}

DEV void gld_lds16(const u16* g, u16* lds) {
    __builtin_amdgcn_global_load_lds(
        (const __attribute__((address_space(1))) void*)g,
        (__attribute__((address_space(3))) void*)lds, 16, 0, 0);
}

#define VMCNT2 asm volatile("s_waitcnt vmcnt(2)" ::: "memory")
#define VMCNT0 asm volatile("s_waitcnt vmcnt(0)" ::: "memory")
#define BAR() __builtin_amdgcn_s_barrier()

DEV u16 h2u(_Float16 h) { union { _Float16 h; u16 u; } v; v.h = h; return v.u; }

// ---------------- Pass A: fp32 -> fp16 cast (X and W) ----------------
struct PrepArgs {
    const float* src[6];
    u16* dst[6];
    int n4[6];
};

__global__ __launch_bounds__(256) void prep_kernel(PrepArgs a) {
    const int z = blockIdx.y;
    const f4v* __restrict__ src = (const f4v*)a.src[z];
    u16x4* __restrict__ dst = (u16x4*)a.dst[z];
    const int n4 = a.n4[z];
    int i = blockIdx.x * blockDim.x + threadIdx.x;
    const int stride = gridDim.x * blockDim.x;
    for (; i < n4; i += stride) {
        f4v x = src[i];
        u16x4 d;
#pragma unroll
        for (int c = 0; c < 4; ++c) d[c] = h2u((_Float16)x[c]);
        dst[i] = d;
    }
}

// ---------------- Pass B: projections — 256x256 tile, 8-wave, 8-phase, fp16 1-term ----------------
struct ProjArgs {
    const u16* xf[3];
    const u16* wf[3];
    u16* outq;
    u16* outk;
    u16* outvt;
};

__global__ __launch_bounds__(512, 2) void proj_kernel(ProjArgs args) {
    __shared__ u16 lds[2][32768];

    const int tid = threadIdx.x;
    const int w = tid >> 6, l = tid & 63;
    const int fr = l & 15, fg = l >> 4;
    const int wa = w >> 2, wb = w & 3;

    const int b0 = blockIdx.x;
    const int swz = (b0 & 7) * 24 + (b0 >> 3);
    const int z = swz >> 6;
    const int r = swz & 63;

    int ta, tb;
    const u16 *A0, *B0;
    if (z < 2) {
        ta = r & 3; tb = r >> 2;
        A0 = args.wf[z];
        B0 = args.xf[z];
    } else {
        ta = r >> 2; tb = r & 3;
        A0 = args.xf[2];
        B0 = args.wf[2];
    }

    const int s_r = tid >> 3;
    const int s_c = (((tid & 7) ^ (s_r & 7)) << 3);
    const size_t aoff = (size_t)(ta * 256 + s_r) * 1024 + s_c;
    const size_t boff = (size_t)(tb * 256 + s_r) * 1024 + s_c;

    const int abase = (wa * 128 + fr) * 64;
    const int bbase = 16384 + (wb * 64 + fr) * 64;
    const int sl0 = ((fg) ^ (fr & 7)) << 3;
    const int sl1 = ((4 + fg) ^ (fr & 7)) << 3;

    f32x4 acc[8][4];
#pragma unroll
    for (int mi = 0; mi < 8; ++mi)
#pragma unroll
        for (int ni = 0; ni < 4; ++ni)
            acc[mi][ni] = (f32x4){0.f, 0.f, 0.f, 0.f};

#define STAGE2(SRC, OFFBASE, REGION, HALF, BUFN, KTN)                               \
    do {                                                                            \
        _Pragma("unroll")                                                           \
        for (int j = 0; j < 2; ++j) {                                               \
            gld_lds16((SRC) + (OFFBASE) + (size_t)((HALF) * 128 + j * 64) * 1024    \
                           + (size_t)(KTN) * 64,                                    \
                      &lds[BUFN][(REGION) + (HALF) * 8192 + j * 4096 + w * 512]);   \
        }                                                                           \
    } while (0)

#pragma unroll
    for (int h = 0; h < 2; ++h) {
#pragma unroll
        for (int j = 0; j < 2; ++j) {
            gld_lds16(A0 + aoff + (size_t)(h * 128 + j * 64) * 1024,
                      &lds[0][h * 8192 + j * 4096 + w * 512]);
            gld_lds16(B0 + boff + (size_t)(h * 128 + j * 64) * 1024,
                      &lds[0][16384 + h * 8192 + j * 4096 + w * 512]);
        }
    }

#define PHASE(MQ0, STAGECALL)                                                       \
    do {                                                                            \
        if (more) STAGECALL;                                                        \
        f16x8 p00 = *(const f16x8*)&Lb[abase + (MQ0) * 1024 + sl0];                 \
        f16x8 p01 = *(const f16x8*)&Lb[abase + (MQ0) * 1024 + sl1];                 \
        f16x8 p10 = *(const f16x8*)&Lb[abase + (MQ0 + 1) * 1024 + sl0];             \
        f16x8 p11 = *(const f16x8*)&Lb[abase + (MQ0 + 1) * 1024 + sl1];             \
        BAR();                                                                      \
        __builtin_amdgcn_s_setprio(1);                                              \
        _Pragma("unroll")                                                           \
        for (int ni = 0; ni < 4; ++ni) {                                            \
            acc[MQ0][ni] = mfma16h(p00, Bf0[ni], acc[MQ0][ni]);                     \
            acc[MQ0][ni] = mfma16h(p01, Bf1[ni], acc[MQ0][ni]);                     \
            acc[MQ0 + 1][ni] = mfma16h(p10, Bf0[ni], acc[MQ0 + 1][ni]);             \
            acc[MQ0 + 1][ni] = mfma16h(p11, Bf1[ni], acc[MQ0 + 1][ni]);             \
        }                                                                           \
        __builtin_amdgcn_s_setprio(0);                                              \
        BAR();                                                                      \
    } while (0)

#pragma unroll 1
    for (int t = 0; t < 16; ++t) {
        const int buf = t & 1;
        const int nbuf = buf ^ 1;
        const int tn = t + 1;
        const bool more = (tn < 16);
        const int ktn = tn;
        const u16* An = A0;
        const u16* Bn = B0;
        const u16* Lb = &lds[buf][0];

        f16x8 Bf0[4], Bf1[4];

        if (more) STAGE2(An, aoff, 0, 0, nbuf, ktn);
        if (more) { VMCNT2; } else { VMCNT0; }
        BAR();
        {
            f16x8 a00 = *(const f16x8*)&Lb[abase + sl0];
            f16x8 a01 = *(const f16x8*)&Lb[abase + sl1];
            f16x8 a10 = *(const f16x8*)&Lb[abase + 1024 + sl0];
            f16x8 a11 = *(const f16x8*)&Lb[abase + 1024 + sl1];
#pragma unroll
            for (int ni = 0; ni < 4; ++ni) {
                Bf0[ni] = *(const f16x8*)&Lb[bbase + ni * 1024 + sl0];
                Bf1[ni] = *(const f16x8*)&Lb[bbase + ni * 1024 + sl1];
            }
            BAR();
            __builtin_amdgcn_s_setprio(1);
#pragma unroll
            for (int ni = 0; ni < 4; ++ni) {
                acc[0][ni] = mfma16h(a00, Bf0[ni], acc[0][ni]);
                acc[0][ni] = mfma16h(a01, Bf1[ni], acc[0][ni]);
                acc[1][ni] = mfma16h(a10, Bf0[ni], acc[1][ni]);
                acc[1][ni] = mfma16h(a11, Bf1[ni], acc[1][ni]);
            }
            __builtin_amdgcn_s_setprio(0);
            BAR();
        }
        PHASE(2, STAGE2(An, aoff, 0, 1, nbuf, ktn));
        PHASE(4, STAGE2(Bn, boff, 16384, 0, nbuf, ktn));
        PHASE(6, STAGE2(Bn, boff, 16384, 1, nbuf, ktn));
    }
#undef PHASE
#undef STAGE2

    if (z < 2) {
        u16* outp = (z == 0) ? args.outq : args.outk;
#pragma unroll
        for (int mq = 0; mq < 8; ++mq) {
#pragma unroll
            for (int ni = 0; ni < 4; ++ni) {
                const int e0 = ta * 256 + wa * 128 + mq * 16 + fg * 4;
                const int m = tb * 256 + wb * 64 + ni * 16 + fr;
                const int n = (m >> 11) * 16 + (e0 >> 6);
                const int s = m & 2047;
                u16x4 pk;
#pragma unroll
                for (int rr = 0; rr < 4; ++rr) pk[rr] = f2bf(acc[mq][ni][rr]);
                *(u16x4*)&outp[((size_t)(n * 2048 + s)) * 64 + (e0 & 63)] = pk;
            }
        }
    } else {
        u16* outp = args.outvt;
#pragma unroll
        for (int mq = 0; mq < 8; ++mq) {
#pragma unroll
            for (int ni = 0; ni < 4; ++ni) {
                const int m0 = ta * 256 + wa * 128 + mq * 16 + fg * 4;
                const int e = tb * 256 + wb * 64 + ni * 16 + fr;
                const int n = (m0 >> 11) * 16 + (e >> 6);
                u16x4 pk;
#pragma unroll
                for (int rr = 0; rr < 4; ++rr) pk[rr] = f2bf(acc[mq][ni][rr]);
                *(u16x4*)&outp[((size_t)(n * 64 + (e & 63))) * 2048 + (m0 & 2047)] = pk;
            }
        }
    }
}

// ---------------- Pass C: flash attention ----------------
// Single barrier per chunk (pre-write barrier is redundant: writes target buf^1,
// ordered vs its readers by the PREVIOUS chunk's end-barrier). Staging hoisted
// before PV (ds_writes overlap PV MFMA; global loads get +1 phase of flight).
// setprio(1) around MFMA clusters (T5).
__global__ __launch_bounds__(512, 4) void attn_kernel(const u16* __restrict__ qh,
                                                      const u16* __restrict__ kh,
                                                      const u16* __restrict__ vt,
                                                      float* __restrict__ out) {
    __shared__ u16 lds[2][16384];

    const int tid = threadIdx.x;
    const int w = tid >> 6, l = tid & 63;
    const int fr = l & 15, fg = l >> 4;

    const int b = blockIdx.x;
    const int n = (b & 7) * 4 + ((b >> 3) >> 4);
    const int qt = (b >> 3) & 15;
    const int qbase = qt * 128 + w * 16;
    const float cs = 0.125f * 1.44269504088896f;

    const u16* khn = kh + (size_t)n * 2048 * 64;
    const u16* vtn = vt + (size_t)n * 64 * 2048;

    const u16* qrow = qh + ((size_t)n * 2048 + qbase + fr) * 64;
    bf16x8 aq0 = *(const bf16x8*)(qrow + fg * 8);
    bf16x8 aq1 = *(const bf16x8*)(qrow + 32 + fg * 8);

    bf16x8 ones;
#pragma unroll
    for (int j = 0; j < 8; ++j) ones[j] = (short)0x3F80;

    const int krow_s = tid >> 2;
    const int kcol_s = (tid & 3) * 16;
    const int kg_s = ((tid >> 2) & 3) + 4 * ((tid >> 5) & 1);
    const int kws0 = ((((tid & 3) * 2 + 0) + kg_s) & 7) * 8;
    const int kws1 = ((((tid & 3) * 2 + 1) + kg_s) & 7) * 8;
    const int vrow_s = tid >> 3;
    const int vcol_s = (tid & 7) * 16;
    const int vg_s = (tid >> 3) & 7;
    const int vws0 = ((((tid & 7) * 2 + 0) + vg_s) & 15) * 8;
    const int vws1 = ((((tid & 7) * 2 + 1) + vg_s) & 15) * 8;

    const int rbase = ((fr >> 2) << 3) + (fr & 3);
    const int kg_r = (fr & 3) + 4 * ((fr >> 2) & 1);
    const int ksl0 = (((fg + 0) + kg_r) & 7) * 8;
    const int ksl1 = (((fg + 4) + kg_r) & 7) * 8;
    const int vg_r = fr & 7;

    f32x4 acc[5];
#pragma unroll
    for (int dc = 0; dc < 5; ++dc) acc[dc] = (f32x4){0.f, 0.f, 0.f, 0.f};
    float mrun = -INFINITY;

    bf16x8 kr0, kr1, vr0, vr1;

#define STAGE_LOAD(kb_) do {                                                       \
        const u16* ksrc = khn + ((size_t)((kb_) * 128 + krow_s)) * 64 + kcol_s;    \
        kr0 = *(const bf16x8*)(ksrc);                                              \
        kr1 = *(const bf16x8*)(ksrc + 8);                                          \
        const u16* vsrc = vtn + (size_t)vrow_s * 2048 + (kb_) * 128 + vcol_s;      \
        vr0 = *(const bf16x8*)(vsrc);                                              \
        vr1 = *(const bf16x8*)(vsrc + 8);                                          \
    } while (0)

#define STAGE_WRITE(buf_) do {                                                     \
        u16* kp = &lds[buf_][0];                                                   \
        *(bf16x8*)&kp[krow_s * 64 + kws0] = kr0;                                   \
        *(bf16x8*)&kp[krow_s * 64 + kws1] = kr1;                                   \
        u16* vp = &lds[buf_][8192];                                                \
        *(bf16x8*)&vp[vrow_s * 128 + vws0] = vr0;                                  \
        *(bf16x8*)&vp[vrow_s * 128 + vws1] = vr1;                                  \
    } while (0)

    STAGE_LOAD(0);
    STAGE_WRITE(0);
    STAGE_LOAD(1);
    __syncthreads();

    for (int kb = 0; kb < 16; ++kb) {
        const int cur = kb & 1;
        const u16* Kb = &lds[cur][0];
        const u16* Vb = &lds[cur][8192];

        // ---- QK^T ----
        f32x4 sf[8];
        __builtin_amdgcn_s_setprio(1);
#pragma unroll
        for (int c = 0; c < 8; ++c) {
            const int rr = ((c >> 1) << 5) + ((c & 1) << 2) + rbase;
            f32x4 s = (f32x4){0.f, 0.f, 0.f, 0.f};
            s = mfma16(*(const bf16x8*)&Kb[rr * 64 + ksl0], aq0, s);
            s = mfma16(*(const bf16x8*)&Kb[rr * 64 + ksl1], aq1, s);
            sf[c] = s;
        }
        __builtin_amdgcn_s_setprio(0);

        // ---- row max ----
        f32x4 cmv = sf[0];
#pragma unroll
        for (int c = 1; c < 8; ++c)
#pragma unroll
            for (int rr = 0; rr < 4; ++rr) cmv[rr] = fmaxf(cmv[rr], sf[c][rr]);
        float cm = fmaxf(fmaxf(cmv[0], cmv[1]), fmaxf(cmv[2], cmv[3]));
        cm = fmaxf(cm, __shfl_xor(cm, 16, 64));
        cm = fmaxf(cm, __shfl_xor(cm, 32, 64));

        if (__any(cm > mrun)) {
            float mnew = fmaxf(mrun, cm);
            float sc = fexp2(cs * (mrun - mnew));
            mrun = mnew;
#pragma unroll
            for (int dc = 0; dc < 5; ++dc)
#pragma unroll
                for (int rr = 0; rr < 4; ++rr) acc[dc][rr] *= sc;
        }

        // ---- p = exp2(cs*s - cs*m) ----
        const float negm = -cs * mrun;
#pragma unroll
        for (int c = 0; c < 8; ++c) {
#pragma unroll
            for (int rr = 0; rr < 4; ++rr)
                sf[c][rr] = fexp2(fmaf(cs, sf[c][rr], negm));
        }

        // ---- stage next chunk early (overlaps PV; loads get extra flight) ----
        if (kb < 15) {
            STAGE_WRITE(cur ^ 1);
            if (kb < 14) STAGE_LOAD(kb + 2);
        }

        // ---- PV ----
        __builtin_amdgcn_s_setprio(1);
#pragma unroll
        for (int pw = 0; pw < 4; ++pw) {
            union { bf16x8 v; uint32_t u[4]; } ap;
#pragma unroll
            for (int q2 = 0; q2 < 4; ++q2) {
                float lo = sf[2 * pw + (q2 >> 1)][(q2 & 1) * 2 + 0];
                float hi = sf[2 * pw + (q2 >> 1)][(q2 & 1) * 2 + 1];
                asm("v_cvt_pk_bf16_f32 %0, %1, %2" : "=v"(ap.u[q2]) : "v"(lo), "v"(hi));
            }
#pragma unroll
            for (int dc = 0; dc < 4; ++dc) {
                const int vsl = (((pw * 4 + fg) + vg_r) & 15) * 8;
                acc[dc] = mfma16(*(const bf16x8*)&Vb[(dc * 16 + fr) * 128 + vsl],
                                 ap.v, acc[dc]);
            }
            acc[4] = mfma16(ones, ap.v, acc[4]);
        }
        __builtin_amdgcn_s_setprio(0);

        // ---- single barrier per chunk ----
        if (kb < 15) __syncthreads();
    }

    const float inv = 1.f / acc[4][0];
    const int bq = n & 1;
    const int col0 = (n >> 1) * 64;
    float* orow = out + ((size_t)bq * 2048 + qbase + fr) * 1024 + col0 + fg * 4;
#pragma unroll
    for (int dblk = 0; dblk < 4; ++dblk) {
        f4v o;
#pragma unroll
        for (int rr = 0; rr < 4; ++rr) o[rr] = acc[dblk][rr] * inv;
        *(f4v*)&orow[dblk * 16] = o;
    }
#undef STAGE_LOAD
#undef STAGE_WRITE
}

// ---------------- launch ----------------
extern "C" void kernel_launch(void* const* d_in, const int* in_sizes, int n_in,
                              void* d_out, int out_size, void* d_ws, size_t ws_size,
                              hipStream_t stream) {
    (void)n_in; (void)out_size; (void)ws_size;
    const float* q  = (const float*)d_in[0];
    const float* k  = (const float*)d_in[1];
    const float* v  = (const float*)d_in[2];
    const float* Wq = (const float*)d_in[3];
    const float* Wk = (const float*)d_in[4];
    const float* Wv = (const float*)d_in[5];

    uint8_t* ws = (uint8_t*)d_ws;
    const size_t MB = 1024ull * 1024ull;
    u16* xq_f = (u16*)(ws + 0 * MB);
    u16* xk_f = (u16*)(ws + 8 * MB);
    u16* xv_f = (u16*)(ws + 16 * MB);
    u16* wq_f = (u16*)(ws + 24 * MB);
    u16* wk_f = (u16*)(ws + 26 * MB);
    u16* wv_f = (u16*)(ws + 28 * MB);
    u16* qh   = (u16*)(ws + 30 * MB);
    u16* kh   = (u16*)(ws + 38 * MB);
    u16* vt   = (u16*)(ws + 46 * MB);

    PrepArgs pp;
    pp.src[0] = q;  pp.src[1] = k;  pp.src[2] = v;
    pp.src[3] = Wq; pp.src[4] = Wk; pp.src[5] = Wv;
    pp.dst[0] = xq_f; pp.dst[1] = xk_f; pp.dst[2] = xv_f;
    pp.dst[3] = wq_f; pp.dst[4] = wk_f; pp.dst[5] = wv_f;
    pp.n4[0] = pp.n4[1] = pp.n4[2] = in_sizes[0] / 4;
    pp.n4[3] = pp.n4[4] = pp.n4[5] = in_sizes[3] / 4;
    prep_kernel<<<dim3(1024, 6), 256, 0, stream>>>(pp);

    ProjArgs pa;
    pa.xf[0] = xq_f; pa.xf[1] = xk_f; pa.xf[2] = xv_f;
    pa.wf[0] = wq_f; pa.wf[1] = wk_f; pa.wf[2] = wv_f;
    pa.outq = qh; pa.outk = kh; pa.outvt = vt;
    proj_kernel<<<dim3(192), 512, 0, stream>>>(pa);

    attn_kernel<<<dim3(512), 512, 0, stream>>>(qh, kh, vt, (float*)d_out);
}